// Round 3
// baseline (1152.638 us; speedup 1.0000x reference)
//
#include <hip/hip_runtime.h>
#include <stdint.h>

#define B_    2
#define S_    2048
#define H_    4096
#define NH_   32
#define NKV_  2
#define HD_   128
#define ROT_  64
#define QKVD  4608          // (NH + 2*NKV) * HD
#define MROWS 4096          // B*S

typedef __attribute__((ext_vector_type(8))) __bf16 bf16x8;
typedef __attribute__((ext_vector_type(4))) float f32x4;

__device__ __forceinline__ unsigned short f2bf(float f) {
    union { float f; unsigned u; } c; c.f = f;
    unsigned u = c.u;
    u += 0x7fffu + ((u >> 16) & 1u);          // round-to-nearest-even
    return (unsigned short)(u >> 16);
}

__device__ __forceinline__ void gload_lds16(const void* g, void* l) {
    __builtin_amdgcn_global_load_lds(
        (__attribute__((address_space(1))) void*)g,
        (__attribute__((address_space(3))) void*)l, 16, 0, 0);
}

// ---------------- prep: fp32 -> bf16 straight copy ----------------
__global__ __launch_bounds__(256) void convert_bf16(const float* __restrict__ src,
                                                    unsigned short* __restrict__ dst,
                                                    int n4) {
    int i = blockIdx.x * 256 + threadIdx.x;
    if (i < n4) {
        f32x4 v = ((const f32x4*)src)[i];
        ushort4 o;
        o.x = f2bf(v[0]); o.y = f2bf(v[1]); o.z = f2bf(v[2]); o.w = f2bf(v[3]);
        ((ushort4*)dst)[i] = o;
    }
}

// ---------------- prep: fp32 [K][N] -> bf16 [N][K] transpose ----------------
__global__ __launch_bounds__(256) void transpose_bf16(const float* __restrict__ src,
                                                      unsigned short* __restrict__ dst,
                                                      int K, int N) {
    __shared__ float tile[32][33];
    int n0 = blockIdx.x * 32, k0 = blockIdx.y * 32;
    int tx = threadIdx.x & 31, ty = threadIdx.x >> 5;   // ty: 0..7
#pragma unroll
    for (int i = 0; i < 4; i++)
        tile[ty + i * 8][tx] = src[(size_t)(k0 + ty + i * 8) * N + n0 + tx];
    __syncthreads();
#pragma unroll
    for (int i = 0; i < 4; i++)
        dst[(size_t)(n0 + ty + i * 8) * K + k0 + tx] = f2bf(tile[tx][ty + i * 8]);
}

// ---------------- GEMM: A[M][K] bf16 row-major, BT[N][K] bf16, C fp32 ----------------
template <int HAS_BIAS>
__global__ __launch_bounds__(256) void gemm_bt(const unsigned short* __restrict__ A,
                                               const unsigned short* __restrict__ BT,
                                               const float* __restrict__ bias,
                                               float* __restrict__ C,
                                               int M, int N, int K) {
    __shared__ __align__(16) unsigned short As[128 * 32];
    __shared__ __align__(16) unsigned short Bs[128 * 32];
    int tid = threadIdx.x;
    int lane = tid & 63, wave = tid >> 6;
    int quad = lane >> 4, lrow = lane & 15;
    int m0 = blockIdx.y * 128, n0 = blockIdx.x * 128;
    int wm = (wave >> 1) * 64, wn = (wave & 1) * 64;

    f32x4 acc[4][4];
#pragma unroll
    for (int mt = 0; mt < 4; mt++)
#pragma unroll
        for (int nt = 0; nt < 4; nt++) acc[mt][nt] = (f32x4){0.f, 0.f, 0.f, 0.f};

    int li0 = tid, li1 = 256 + tid;
    const unsigned short* ga0 = A + (size_t)(m0 + (li0 >> 2)) * K + (li0 & 3) * 8;
    const unsigned short* ga1 = A + (size_t)(m0 + (li1 >> 2)) * K + (li1 & 3) * 8;
    const unsigned short* gb0 = BT + (size_t)(n0 + (li0 >> 2)) * K + (li0 & 3) * 8;
    const unsigned short* gb1 = BT + (size_t)(n0 + (li1 >> 2)) * K + (li1 & 3) * 8;
    unsigned short* la0 = &As[(li0 & ~63) * 8];
    unsigned short* la1 = &As[(li1 & ~63) * 8];
    unsigned short* lb0 = &Bs[(li0 & ~63) * 8];
    unsigned short* lb1 = &Bs[(li1 & ~63) * 8];

    for (int k0 = 0; k0 < K; k0 += 32) {
        gload_lds16(ga0 + k0, la0);
        gload_lds16(ga1 + k0, la1);
        gload_lds16(gb0 + k0, lb0);
        gload_lds16(gb1 + k0, lb1);
        __syncthreads();
        bf16x8 af[4], bfr[4];
#pragma unroll
        for (int mt = 0; mt < 4; mt++)
            af[mt] = *(const bf16x8*)&As[(wm + mt * 16 + lrow) * 32 + quad * 8];
#pragma unroll
        for (int nt = 0; nt < 4; nt++)
            bfr[nt] = *(const bf16x8*)&Bs[(wn + nt * 16 + lrow) * 32 + quad * 8];
#pragma unroll
        for (int mt = 0; mt < 4; mt++)
#pragma unroll
            for (int nt = 0; nt < 4; nt++)
                acc[mt][nt] = __builtin_amdgcn_mfma_f32_16x16x32_bf16(af[mt], bfr[nt],
                                                                      acc[mt][nt], 0, 0, 0);
        __syncthreads();
    }
#pragma unroll
    for (int mt = 0; mt < 4; mt++) {
        int gm = m0 + wm + mt * 16 + quad * 4;
#pragma unroll
        for (int nt = 0; nt < 4; nt++) {
            int gn = n0 + wn + nt * 16 + lrow;
            float bv = HAS_BIAS ? bias[gn] : 0.f;
#pragma unroll
            for (int r = 0; r < 4; r++)
                C[(size_t)(gm + r) * N + gn] = acc[mt][nt][r] + bv;
        }
    }
}

// ---------------- GEMM1 with fused bias + RoPE + pack epilogue ----------------
// A = hidden bf16 [4096][4096], BT = WqkvT bf16 [4608][4096].
// n-tile (128 wide) == one head. Outputs:
//  Qb: [b][h][s][d] bf16, scaled by 1/sqrt(128)*log2(e)
//  Kb: [b][kvh][s][swz d]   pos = ((d>>3)^(s&7))*8 + (d&7)
//  Vb: [b][kvh][d][swz s]   pos = (s>>6)*64 + ((((s>>3)&7)^(d&7))<<3) + (s&7)
__global__ __launch_bounds__(256) void gemm_qkv(const unsigned short* __restrict__ A,
                                                const unsigned short* __restrict__ BT,
                                                const float* __restrict__ bias,
                                                unsigned short* __restrict__ Qb,
                                                unsigned short* __restrict__ Kb,
                                                unsigned short* __restrict__ Vb) {
    const int K = H_, N = QKVD;
    __shared__ __align__(16) unsigned short As[128 * 32];
    __shared__ __align__(16) unsigned short Bs[128 * 32];
    int tid = threadIdx.x;
    int lane = tid & 63, wave = tid >> 6;
    int quad = lane >> 4, lrow = lane & 15;
    int m0 = blockIdx.y * 128, n0 = blockIdx.x * 128;
    int head = blockIdx.x;
    int wm = (wave >> 1) * 64, wn = (wave & 1) * 64;

    f32x4 acc[4][4];
#pragma unroll
    for (int mt = 0; mt < 4; mt++)
#pragma unroll
        for (int nt = 0; nt < 4; nt++) acc[mt][nt] = (f32x4){0.f, 0.f, 0.f, 0.f};

    int li0 = tid, li1 = 256 + tid;
    const unsigned short* ga0 = A + (size_t)(m0 + (li0 >> 2)) * K + (li0 & 3) * 8;
    const unsigned short* ga1 = A + (size_t)(m0 + (li1 >> 2)) * K + (li1 & 3) * 8;
    const unsigned short* gb0 = BT + (size_t)(n0 + (li0 >> 2)) * K + (li0 & 3) * 8;
    const unsigned short* gb1 = BT + (size_t)(n0 + (li1 >> 2)) * K + (li1 & 3) * 8;
    unsigned short* la0 = &As[(li0 & ~63) * 8];
    unsigned short* la1 = &As[(li1 & ~63) * 8];
    unsigned short* lb0 = &Bs[(li0 & ~63) * 8];
    unsigned short* lb1 = &Bs[(li1 & ~63) * 8];

    for (int k0 = 0; k0 < K; k0 += 32) {
        gload_lds16(ga0 + k0, la0);
        gload_lds16(ga1 + k0, la1);
        gload_lds16(gb0 + k0, lb0);
        gload_lds16(gb1 + k0, lb1);
        __syncthreads();
        bf16x8 af[4], bfr[4];
#pragma unroll
        for (int mt = 0; mt < 4; mt++)
            af[mt] = *(const bf16x8*)&As[(wm + mt * 16 + lrow) * 32 + quad * 8];
#pragma unroll
        for (int nt = 0; nt < 4; nt++)
            bfr[nt] = *(const bf16x8*)&Bs[(wn + nt * 16 + lrow) * 32 + quad * 8];
#pragma unroll
        for (int mt = 0; mt < 4; mt++)
#pragma unroll
            for (int nt = 0; nt < 4; nt++)
                acc[mt][nt] = __builtin_amdgcn_mfma_f32_16x16x32_bf16(af[mt], bfr[nt],
                                                                      acc[mt][nt], 0, 0, 0);
        __syncthreads();
    }

    const float QSCALE = 0.08838834764831843f * 1.4426950408889634f;
#pragma unroll
    for (int mt = 0; mt < 4; mt++) {
        int gm = m0 + wm + mt * 16 + quad * 4;
        int bb = gm >> 11;
        int srow = gm & (S_ - 1);
#pragma unroll
        for (int nt = 0; nt < 4; nt++) {
            int dcol = wn + nt * 16 + lrow;
            float bv = bias[n0 + dcol];
            float vals[4];
#pragma unroll
            for (int r = 0; r < 4; r++) vals[r] = acc[mt][nt][r] + bv;
            if (head < 34 && dcol < ROT_) {     // RoPE (wave-uniform branch)
                int p = dcol >> 1;
                float inv = exp2f(-(float)p * 0.41524101186092035f);
                int odd = dcol & 1;
#pragma unroll
                for (int r = 0; r < 4; r++) {
                    float partner = __shfl_xor(vals[r], 1);
                    float sn, cs;
                    __sincosf((float)(srow + r) * inv, &sn, &cs);
                    vals[r] = odd ? (vals[r] * cs + partner * sn)
                                  : (vals[r] * cs - partner * sn);
                }
            }
            if (head < 32) {
                unsigned short* dst =
                    Qb + ((size_t)(bb * NH_ + head) * S_ + srow) * HD_ + dcol;
#pragma unroll
                for (int r = 0; r < 4; r++) dst[r * HD_] = f2bf(vals[r] * QSCALE);
            } else if (head < 34) {
                size_t base = ((size_t)(bb * NKV_ + head - 32) * S_ + srow) * HD_;
#pragma unroll
                for (int r = 0; r < 4; r++)
                    Kb[base + r * HD_ + (((dcol >> 3) ^ ((srow + r) & 7)) << 3) +
                       (dcol & 7)] = f2bf(vals[r]);
            } else {
                size_t base = ((size_t)(bb * NKV_ + head - 34) * HD_ + dcol) * S_;
#pragma unroll
                for (int r = 0; r < 4; r++) {
                    int s = srow + r;
                    Vb[base + ((s >> 6) << 6) + ((((s >> 3) & 7) ^ (dcol & 7)) << 3) +
                       (s & 7)] = f2bf(vals[r]);
                }
            }
        }
    }
}

// ---------------- flash attention v3: 128 q-rows per block ----------------
__global__ __launch_bounds__(256, 3) void flash3(const unsigned short* __restrict__ Qb,
                                                 const unsigned short* __restrict__ Kb,
                                                 const unsigned short* __restrict__ Vb,
                                                 unsigned short* __restrict__ ctxb) {
    int qblk = (int)(gridDim.x - 1) - blockIdx.x;   // heavy blocks first
    int h = blockIdx.y, b = blockIdx.z;
    int tid = threadIdx.x, lane = tid & 63, wave = tid >> 6;
    int quad = lane >> 4, lrow = lane & 15;
    int bkvh = b * NKV_ + (h >> 4);
    int lw3 = lrow & 7;

    __shared__ __align__(16) unsigned short Ks[64 * 128];   // [key][swz d]   16KB
    __shared__ __align__(16) unsigned short Vt[128 * 64];   // [d][swz key]   16KB
    __shared__ __align__(16) unsigned short Ps[4][32 * 64]; // per-wave       16KB

    int q0 = qblk * 128 + wave * 32;    // wave's 32 q rows (2 m-tiles)

    bf16x8 qf[2][4];
#pragma unroll
    for (int m = 0; m < 2; m++) {
        const unsigned short* qr =
            Qb + ((size_t)(b * NH_ + h) * S_ + q0 + m * 16 + lrow) * HD_ + quad * 8;
#pragma unroll
        for (int c = 0; c < 4; c++) qf[m][c] = *(const bf16x8*)(qr + c * 32);
    }

    float m_i[2][4], l_i[2][4];
    f32x4 oacc[2][8];
#pragma unroll
    for (int m = 0; m < 2; m++)
#pragma unroll
        for (int r = 0; r < 4; r++) { m_i[m][r] = -1e30f; l_i[m][r] = 0.f; }
#pragma unroll
    for (int m = 0; m < 2; m++)
#pragma unroll
        for (int t = 0; t < 8; t++) oacc[m][t] = (f32x4){0.f, 0.f, 0.f, 0.f};

    const unsigned short* Kg = Kb + (size_t)bkvh * S_ * HD_;
    const unsigned short* Vg = Vb + (size_t)bkvh * HD_ * S_;

    int nkt = 2 * qblk + 2;
    for (int kt = 0; kt < nkt; kt++) {
        int ks0 = kt * 64;
        {   // stage K: wave stages keys [wave*16, +16)
            const unsigned short* g =
                Kg + (size_t)(ks0 + wave * 16 + (lane >> 4)) * HD_ + (lane & 15) * 8;
            unsigned short* l = &Ks[wave * 16 * 128];
#pragma unroll
            for (int i = 0; i < 4; i++)
                gload_lds16(g + i * 4 * 128, l + i * 4 * 128);
        }
        {   // stage V: wave stages dims [wave*32, +32)
            const unsigned short* g =
                Vg + (size_t)(wave * 32 + (lane >> 3)) * S_ + ks0 + (lane & 7) * 8;
            unsigned short* l = &Vt[wave * 32 * 64];
#pragma unroll
            for (int i = 0; i < 4; i++)
                gload_lds16(g + (size_t)i * 8 * S_, l + i * 8 * 64);
        }
        __syncthreads();

        if (ks0 <= q0 + 31) {
            f32x4 s0[4], s1[4];
#pragma unroll
            for (int n = 0; n < 4; n++) {
                s0[n] = (f32x4){0.f, 0.f, 0.f, 0.f};
                s1[n] = (f32x4){0.f, 0.f, 0.f, 0.f};
            }
#pragma unroll
            for (int kc = 0; kc < 4; kc++)
#pragma unroll
                for (int n = 0; n < 4; n++) {
                    bf16x8 kf = *(const bf16x8*)
                        &Ks[(n * 16 + lrow) * 128 + (((kc * 4 + quad) ^ lw3) << 3)];
                    s0[n] = __builtin_amdgcn_mfma_f32_16x16x32_bf16(qf[0][kc], kf, s0[n], 0, 0, 0);
                    s1[n] = __builtin_amdgcn_mfma_f32_16x16x32_bf16(qf[1][kc], kf, s1[n], 0, 0, 0);
                }
            if (ks0 + 63 > q0) {    // diagonal region: causal mask
#pragma unroll
                for (int n = 0; n < 4; n++)
#pragma unroll
                    for (int r = 0; r < 4; r++) {
                        int key = ks0 + n * 16 + lrow;
                        if (key > q0 + quad * 4 + r)      s0[n][r] = -1e30f;
                        if (key > q0 + 16 + quad * 4 + r) s1[n][r] = -1e30f;
                    }
            }
            float alpha0[4], alpha1[4];
#pragma unroll
            for (int r = 0; r < 4; r++) {
                float mx = fmaxf(fmaxf(s0[0][r], s0[1][r]), fmaxf(s0[2][r], s0[3][r]));
                mx = fmaxf(mx, __shfl_xor(mx, 1));
                mx = fmaxf(mx, __shfl_xor(mx, 2));
                mx = fmaxf(mx, __shfl_xor(mx, 4));
                mx = fmaxf(mx, __shfl_xor(mx, 8));
                float mn = fmaxf(m_i[0][r], mx);
                alpha0[r] = exp2f(m_i[0][r] - mn);
                m_i[0][r] = mn;
                float rs = 0.f;
#pragma unroll
                for (int n = 0; n < 4; n++) { s0[n][r] = exp2f(s0[n][r] - mn); rs += s0[n][r]; }
                rs += __shfl_xor(rs, 1);
                rs += __shfl_xor(rs, 2);
                rs += __shfl_xor(rs, 4);
                rs += __shfl_xor(rs, 8);
                l_i[0][r] = l_i[0][r] * alpha0[r] + rs;
            }
#pragma unroll
            for (int r = 0; r < 4; r++) {
                float mx = fmaxf(fmaxf(s1[0][r], s1[1][r]), fmaxf(s1[2][r], s1[3][r]));
                mx = fmaxf(mx, __shfl_xor(mx, 1));
                mx = fmaxf(mx, __shfl_xor(mx, 2));
                mx = fmaxf(mx, __shfl_xor(mx, 4));
                mx = fmaxf(mx, __shfl_xor(mx, 8));
                float mn = fmaxf(m_i[1][r], mx);
                alpha1[r] = exp2f(m_i[1][r] - mn);
                m_i[1][r] = mn;
                float rs = 0.f;
#pragma unroll
                for (int n = 0; n < 4; n++) { s1[n][r] = exp2f(s1[n][r] - mn); rs += s1[n][r]; }
                rs += __shfl_xor(rs, 1);
                rs += __shfl_xor(rs, 2);
                rs += __shfl_xor(rs, 4);
                rs += __shfl_xor(rs, 8);
                l_i[1][r] = l_i[1][r] * alpha1[r] + rs;
            }
            // P -> LDS (C-layout -> A-layout, swizzled; rows 0..15 = m0, 16..31 = m1)
#pragma unroll
            for (int n = 0; n < 4; n++)
#pragma unroll
                for (int r = 0; r < 4; r++) {
                    int rw = quad * 4 + r;
                    int sw = (((n * 16 + lrow) >> 3) ^ (rw & 7)) << 3;
                    Ps[wave][rw * 64 + sw + lw3] = f2bf(s0[n][r]);
                    Ps[wave][(16 + rw) * 64 + sw + lw3] = f2bf(s1[n][r]);
                }
#pragma unroll
            for (int t = 0; t < 8; t++)
#pragma unroll
                for (int r = 0; r < 4; r++) {
                    oacc[0][t][r] *= alpha0[r];
                    oacc[1][t][r] *= alpha1[r];
                }
            bf16x8 pf00 = *(const bf16x8*)&Ps[wave][lrow * 64 + ((quad ^ lw3) << 3)];
            bf16x8 pf01 = *(const bf16x8*)&Ps[wave][lrow * 64 + (((4 + quad) ^ lw3) << 3)];
            bf16x8 pf10 = *(const bf16x8*)&Ps[wave][(16 + lrow) * 64 + ((quad ^ lw3) << 3)];
            bf16x8 pf11 = *(const bf16x8*)&Ps[wave][(16 + lrow) * 64 + (((4 + quad) ^ lw3) << 3)];
#pragma unroll
            for (int t = 0; t < 8; t++) {
                int dim = t * 16 + lrow;
                bf16x8 v0 = *(const bf16x8*)&Vt[dim * 64 + ((quad ^ lw3) << 3)];
                bf16x8 v1 = *(const bf16x8*)&Vt[dim * 64 + (((4 + quad) ^ lw3) << 3)];
                oacc[0][t] = __builtin_amdgcn_mfma_f32_16x16x32_bf16(pf00, v0, oacc[0][t], 0, 0, 0);
                oacc[0][t] = __builtin_amdgcn_mfma_f32_16x16x32_bf16(pf01, v1, oacc[0][t], 0, 0, 0);
                oacc[1][t] = __builtin_amdgcn_mfma_f32_16x16x32_bf16(pf10, v0, oacc[1][t], 0, 0, 0);
                oacc[1][t] = __builtin_amdgcn_mfma_f32_16x16x32_bf16(pf11, v1, oacc[1][t], 0, 0, 0);
            }
        }
        __syncthreads();
    }
    // epilogue
#pragma unroll
    for (int m = 0; m < 2; m++) {
        float inv[4];
#pragma unroll
        for (int r = 0; r < 4; r++) inv[r] = 1.f / l_i[m][r];
#pragma unroll
        for (int t = 0; t < 8; t++)
#pragma unroll
            for (int r = 0; r < 4; r++) {
                int q = q0 + m * 16 + quad * 4 + r;
                ctxb[(size_t)(b * S_ + q) * (NH_ * HD_) + h * HD_ + t * 16 + lrow] =
                    f2bf(oacc[m][t][r] * inv[r]);
            }
    }
}

// ---------------- launch ----------------
extern "C" void kernel_launch(void* const* d_in, const int* in_sizes, int n_in,
                              void* d_out, int out_size, void* d_ws, size_t ws_size,
                              hipStream_t stream) {
    const float* hidden = (const float*)d_in[0];
    const float* Wqkv = (const float*)d_in[2];
    const float* bqkv = (const float*)d_in[3];
    const float* Wo   = (const float*)d_in[4];
    float* out = (float*)d_out;

    char* ws = (char*)d_ws;
    unsigned short* Xb    = (unsigned short*)ws;                         // 32 MB
    unsigned short* WqkvT = (unsigned short*)(ws + 33554432);            // 36 MB
    unsigned short* Qb    = (unsigned short*)(ws + 71303168);            // 32 MB
    unsigned short* Kb    = (unsigned short*)(ws + 104857600);           //  2 MB
    unsigned short* Vb    = (unsigned short*)(ws + 106954752);           //  2 MB
    unsigned short* ctxb  = (unsigned short*)(ws + 109051904);           // 32 MB
    unsigned short* WoT   = Xb;          // Xb dead after gemm_qkv

    // 1. hidden -> bf16
    convert_bf16<<<16384, 256, 0, stream>>>(hidden, Xb, (MROWS * H_) / 4);
    // 2. Wqkv [4096][4608] -> WqkvT bf16 [4608][4096]
    transpose_bf16<<<dim3(QKVD / 32, H_ / 32), 256, 0, stream>>>(Wqkv, WqkvT, H_, QKVD);
    // 3. QKV projection + bias + RoPE + pack (fused epilogue)
    gemm_qkv<<<dim3(QKVD / 128, MROWS / 128), 256, 0, stream>>>(Xb, WqkvT, bqkv,
                                                                Qb, Kb, Vb);
    // 4. Wo -> WoT bf16 (into Xb region, dead after gemm_qkv)
    transpose_bf16<<<dim3(H_ / 32, H_ / 32), 256, 0, stream>>>(Wo, WoT, NH_ * HD_, H_);
    // 5. flash attention -> ctx bf16
    flash3<<<dim3(S_ / 128, NH_, B_), 256, 0, stream>>>(Qb, Kb, Vb, ctxb);
    // 6. output projection -> d_out fp32
    gemm_bt<0><<<dim3(H_ / 128, MROWS / 128), 256, 0, stream>>>(ctxb, WoT, nullptr, out,
                                                                MROWS, H_, NH_ * HD_);
}

// Round 4
// 840.355 us; speedup vs baseline: 1.3716x; 1.3716x over previous
//
#include <hip/hip_runtime.h>
#include <stdint.h>

#define B_    2
#define S_    2048
#define H_    4096
#define NH_   32
#define NKV_  2
#define HD_   128
#define ROT_  64
#define QKVD  4608          // (NH + 2*NKV) * HD
#define MROWS 4096          // B*S

typedef __attribute__((ext_vector_type(8))) __bf16 bf16x8;
typedef __attribute__((ext_vector_type(4))) float f32x4;

__device__ __forceinline__ unsigned short f2bf(float f) {
    union { float f; unsigned u; } c; c.f = f;
    unsigned u = c.u;
    u += 0x7fffu + ((u >> 16) & 1u);          // round-to-nearest-even
    return (unsigned short)(u >> 16);
}

__device__ __forceinline__ void gload_lds16(const void* g, void* l) {
    __builtin_amdgcn_global_load_lds(
        (__attribute__((address_space(1))) void*)g,
        (__attribute__((address_space(3))) void*)l, 16, 0, 0);
}

// ---------------- prep: fp32 -> bf16 straight copy ----------------
__global__ __launch_bounds__(256) void convert_bf16(const float* __restrict__ src,
                                                    unsigned short* __restrict__ dst,
                                                    int n4) {
    int i = blockIdx.x * 256 + threadIdx.x;
    if (i < n4) {
        f32x4 v = ((const f32x4*)src)[i];
        ushort4 o;
        o.x = f2bf(v[0]); o.y = f2bf(v[1]); o.z = f2bf(v[2]); o.w = f2bf(v[3]);
        ((ushort4*)dst)[i] = o;
    }
}

// ---------------- prep: fp32 [K][N] -> bf16 [N][K] transpose ----------------
__global__ __launch_bounds__(256) void transpose_bf16(const float* __restrict__ src,
                                                      unsigned short* __restrict__ dst,
                                                      int K, int N) {
    __shared__ float tile[32][33];
    int n0 = blockIdx.x * 32, k0 = blockIdx.y * 32;
    int tx = threadIdx.x & 31, ty = threadIdx.x >> 5;   // ty: 0..7
#pragma unroll
    for (int i = 0; i < 4; i++)
        tile[ty + i * 8][tx] = src[(size_t)(k0 + ty + i * 8) * N + n0 + tx];
    __syncthreads();
#pragma unroll
    for (int i = 0; i < 4; i++)
        dst[(size_t)(n0 + ty + i * 8) * K + k0 + tx] = f2bf(tile[tx][ty + i * 8]);
}

// ---------------- GEMM: A[M][K] bf16 row-major, BT[N][K] bf16, C fp32 ----------------
template <int HAS_BIAS>
__global__ __launch_bounds__(256) void gemm_bt(const unsigned short* __restrict__ A,
                                               const unsigned short* __restrict__ BT,
                                               const float* __restrict__ bias,
                                               float* __restrict__ C,
                                               int M, int N, int K) {
    __shared__ __align__(16) unsigned short As[128 * 32];
    __shared__ __align__(16) unsigned short Bs[128 * 32];
    int tid = threadIdx.x;
    int lane = tid & 63, wave = tid >> 6;
    int quad = lane >> 4, lrow = lane & 15;
    int m0 = blockIdx.y * 128, n0 = blockIdx.x * 128;
    int wm = (wave >> 1) * 64, wn = (wave & 1) * 64;

    f32x4 acc[4][4];
#pragma unroll
    for (int mt = 0; mt < 4; mt++)
#pragma unroll
        for (int nt = 0; nt < 4; nt++) acc[mt][nt] = (f32x4){0.f, 0.f, 0.f, 0.f};

    int li0 = tid, li1 = 256 + tid;
    const unsigned short* ga0 = A + (size_t)(m0 + (li0 >> 2)) * K + (li0 & 3) * 8;
    const unsigned short* ga1 = A + (size_t)(m0 + (li1 >> 2)) * K + (li1 & 3) * 8;
    const unsigned short* gb0 = BT + (size_t)(n0 + (li0 >> 2)) * K + (li0 & 3) * 8;
    const unsigned short* gb1 = BT + (size_t)(n0 + (li1 >> 2)) * K + (li1 & 3) * 8;
    unsigned short* la0 = &As[(li0 & ~63) * 8];
    unsigned short* la1 = &As[(li1 & ~63) * 8];
    unsigned short* lb0 = &Bs[(li0 & ~63) * 8];
    unsigned short* lb1 = &Bs[(li1 & ~63) * 8];

    for (int k0 = 0; k0 < K; k0 += 32) {
        gload_lds16(ga0 + k0, la0);
        gload_lds16(ga1 + k0, la1);
        gload_lds16(gb0 + k0, lb0);
        gload_lds16(gb1 + k0, lb1);
        __syncthreads();
        bf16x8 af[4], bfr[4];
#pragma unroll
        for (int mt = 0; mt < 4; mt++)
            af[mt] = *(const bf16x8*)&As[(wm + mt * 16 + lrow) * 32 + quad * 8];
#pragma unroll
        for (int nt = 0; nt < 4; nt++)
            bfr[nt] = *(const bf16x8*)&Bs[(wn + nt * 16 + lrow) * 32 + quad * 8];
#pragma unroll
        for (int mt = 0; mt < 4; mt++)
#pragma unroll
            for (int nt = 0; nt < 4; nt++)
                acc[mt][nt] = __builtin_amdgcn_mfma_f32_16x16x32_bf16(af[mt], bfr[nt],
                                                                      acc[mt][nt], 0, 0, 0);
        __syncthreads();
    }
#pragma unroll
    for (int mt = 0; mt < 4; mt++) {
        int gm = m0 + wm + mt * 16 + quad * 4;
#pragma unroll
        for (int nt = 0; nt < 4; nt++) {
            int gn = n0 + wn + nt * 16 + lrow;
            float bv = HAS_BIAS ? bias[gn] : 0.f;
#pragma unroll
            for (int r = 0; r < 4; r++)
                C[(size_t)(gm + r) * N + gn] = acc[mt][nt][r] + bv;
        }
    }
}

// ---------------- GEMM1 with fused bias + RoPE + pack epilogue ----------------
// A = hidden bf16 [4096][4096], BT = WqkvT bf16 [4608][4096].
// n-tile (128 wide) == one head. Outputs:
//  Qb: [b][h][s][d] bf16, scaled by 1/sqrt(128)*log2(e)
//  Kb: [b][kvh][s][swz d]   pos = ((d>>3)^(s&7))*8 + (d&7)
//  Vb: [b][kvh][d][swz s]   pos = (s>>6)*64 + ((((s>>3)&7)^(d&7))<<3) + (s&7)
__global__ __launch_bounds__(256) void gemm_qkv(const unsigned short* __restrict__ A,
                                                const unsigned short* __restrict__ BT,
                                                const float* __restrict__ bias,
                                                unsigned short* __restrict__ Qb,
                                                unsigned short* __restrict__ Kb,
                                                unsigned short* __restrict__ Vb) {
    const int K = H_;
    __shared__ __align__(16) unsigned short As[128 * 32];
    __shared__ __align__(16) unsigned short Bs[128 * 32];
    int tid = threadIdx.x;
    int lane = tid & 63, wave = tid >> 6;
    int quad = lane >> 4, lrow = lane & 15;
    int m0 = blockIdx.y * 128, n0 = blockIdx.x * 128;
    int head = blockIdx.x;
    int wm = (wave >> 1) * 64, wn = (wave & 1) * 64;

    f32x4 acc[4][4];
#pragma unroll
    for (int mt = 0; mt < 4; mt++)
#pragma unroll
        for (int nt = 0; nt < 4; nt++) acc[mt][nt] = (f32x4){0.f, 0.f, 0.f, 0.f};

    int li0 = tid, li1 = 256 + tid;
    const unsigned short* ga0 = A + (size_t)(m0 + (li0 >> 2)) * K + (li0 & 3) * 8;
    const unsigned short* ga1 = A + (size_t)(m0 + (li1 >> 2)) * K + (li1 & 3) * 8;
    const unsigned short* gb0 = BT + (size_t)(n0 + (li0 >> 2)) * K + (li0 & 3) * 8;
    const unsigned short* gb1 = BT + (size_t)(n0 + (li1 >> 2)) * K + (li1 & 3) * 8;
    unsigned short* la0 = &As[(li0 & ~63) * 8];
    unsigned short* la1 = &As[(li1 & ~63) * 8];
    unsigned short* lb0 = &Bs[(li0 & ~63) * 8];
    unsigned short* lb1 = &Bs[(li1 & ~63) * 8];

    for (int k0 = 0; k0 < K; k0 += 32) {
        gload_lds16(ga0 + k0, la0);
        gload_lds16(ga1 + k0, la1);
        gload_lds16(gb0 + k0, lb0);
        gload_lds16(gb1 + k0, lb1);
        __syncthreads();
        bf16x8 af[4], bfr[4];
#pragma unroll
        for (int mt = 0; mt < 4; mt++)
            af[mt] = *(const bf16x8*)&As[(wm + mt * 16 + lrow) * 32 + quad * 8];
#pragma unroll
        for (int nt = 0; nt < 4; nt++)
            bfr[nt] = *(const bf16x8*)&Bs[(wn + nt * 16 + lrow) * 32 + quad * 8];
#pragma unroll
        for (int mt = 0; mt < 4; mt++)
#pragma unroll
            for (int nt = 0; nt < 4; nt++)
                acc[mt][nt] = __builtin_amdgcn_mfma_f32_16x16x32_bf16(af[mt], bfr[nt],
                                                                      acc[mt][nt], 0, 0, 0);
        __syncthreads();
    }

    const float QSCALE = 0.08838834764831843f * 1.4426950408889634f;
#pragma unroll
    for (int mt = 0; mt < 4; mt++) {
        int gm = m0 + wm + mt * 16 + quad * 4;
        int bb = gm >> 11;
        int srow = gm & (S_ - 1);
#pragma unroll
        for (int nt = 0; nt < 4; nt++) {
            int dcol = wn + nt * 16 + lrow;
            float bv = bias[n0 + dcol];
            float vals[4];
#pragma unroll
            for (int r = 0; r < 4; r++) vals[r] = acc[mt][nt][r] + bv;
            if (head < 34 && dcol < ROT_) {     // RoPE (wave-uniform branch)
                int p = dcol >> 1;
                float inv = exp2f(-(float)p * 0.41524101186092035f);
                int odd = dcol & 1;
#pragma unroll
                for (int r = 0; r < 4; r++) {
                    float partner = __shfl_xor(vals[r], 1);
                    float sn, cs;
                    __sincosf((float)(srow + r) * inv, &sn, &cs);
                    vals[r] = odd ? (vals[r] * cs + partner * sn)
                                  : (vals[r] * cs - partner * sn);
                }
            }
            if (head < 32) {
                unsigned short* dst =
                    Qb + ((size_t)(bb * NH_ + head) * S_ + srow) * HD_ + dcol;
#pragma unroll
                for (int r = 0; r < 4; r++) dst[r * HD_] = f2bf(vals[r] * QSCALE);
            } else if (head < 34) {
                size_t base = ((size_t)(bb * NKV_ + head - 32) * S_ + srow) * HD_;
#pragma unroll
                for (int r = 0; r < 4; r++)
                    Kb[base + r * HD_ + (((dcol >> 3) ^ ((srow + r) & 7)) << 3) +
                       (dcol & 7)] = f2bf(vals[r]);
            } else {
                size_t base = ((size_t)(bb * NKV_ + head - 34) * HD_ + dcol) * S_;
#pragma unroll
                for (int r = 0; r < 4; r++) {
                    int s = srow + r;
                    Vb[base + ((s >> 6) << 6) + ((((s >> 3) & 7) ^ (dcol & 7)) << 3) +
                       (s & 7)] = f2bf(vals[r]);
                }
            }
        }
    }
}

// ---------------- flash attention v4: paired q-blocks for perfect balance ----
// Each workgroup handles qblk = pair and qblk = 31-pair: (pair+1)+(32-pair) = 33
// tile-units for every block -> uniform duration, 4 blocks/CU, no stragglers.
__global__ __launch_bounds__(256, 4) void flash4(const unsigned short* __restrict__ Qb,
                                                 const unsigned short* __restrict__ Kb,
                                                 const unsigned short* __restrict__ Vb,
                                                 unsigned short* __restrict__ ctxb) {
    int pair = blockIdx.x;              // 0..15
    int h = blockIdx.y, b = blockIdx.z;
    int tid = threadIdx.x, lane = tid & 63, wave = tid >> 6;
    int quad = lane >> 4, lrow = lane & 15;
    int bkvh = b * NKV_ + (h >> 4);
    int lw3 = lrow & 7;

    __shared__ __align__(16) unsigned short Ks[64 * 128];   // [key][swz d] 16KB
    __shared__ __align__(16) unsigned short Vt[128 * 64];   // [d][swz key] 16KB
    __shared__ __align__(16) unsigned short Ps[4][16 * 64]; // per-wave      8KB

    const unsigned short* Kg = Kb + (size_t)bkvh * S_ * HD_;
    const unsigned short* Vg = Vb + (size_t)bkvh * HD_ * S_;

#pragma unroll 1
    for (int u = 0; u < 2; u++) {
        int qblk = u ? ((int)(S_ / 64) - 1 - pair) : pair;
        int q0 = qblk * 64 + wave * 16;

        // Q fragments (A-operand): lane holds Q[q0+lrow][c*32 + quad*8 + j]
        bf16x8 qf[4];
        {
            const unsigned short* qr =
                Qb + ((size_t)(b * NH_ + h) * S_ + q0 + lrow) * HD_ + quad * 8;
#pragma unroll
            for (int c = 0; c < 4; c++) qf[c] = *(const bf16x8*)(qr + c * 32);
        }

        float m_i[4], l_i[4];
        f32x4 oacc[8];
#pragma unroll
        for (int r = 0; r < 4; r++) { m_i[r] = -1e30f; l_i[r] = 0.f; }
#pragma unroll
        for (int t = 0; t < 8; t++) oacc[t] = (f32x4){0.f, 0.f, 0.f, 0.f};

        int nkt = qblk + 1;
#pragma unroll 1
        for (int kt = 0; kt < nkt; kt++) {
            int ks0 = kt * 64;
            {   // stage K: wave stages keys [wave*16, +16)
                const unsigned short* g =
                    Kg + (size_t)(ks0 + wave * 16 + (lane >> 4)) * HD_ + (lane & 15) * 8;
                unsigned short* l = &Ks[wave * 16 * 128];
#pragma unroll
                for (int i = 0; i < 4; i++)
                    gload_lds16(g + i * 4 * 128, l + i * 4 * 128);
            }
            {   // stage V: wave stages dims [wave*32, +32)
                const unsigned short* g =
                    Vg + (size_t)(wave * 32 + (lane >> 3)) * S_ + ks0 + (lane & 7) * 8;
                unsigned short* l = &Vt[wave * 32 * 64];
#pragma unroll
                for (int i = 0; i < 4; i++)
                    gload_lds16(g + (size_t)i * 8 * S_, l + i * 8 * 64);
            }
            __syncthreads();

            if (ks0 <= q0 + 15) {
                f32x4 s[4];
#pragma unroll
                for (int n = 0; n < 4; n++) s[n] = (f32x4){0.f, 0.f, 0.f, 0.f};
#pragma unroll
                for (int kc = 0; kc < 4; kc++)
#pragma unroll
                    for (int n = 0; n < 4; n++) {
                        bf16x8 kf = *(const bf16x8*)
                            &Ks[(n * 16 + lrow) * 128 + (((kc * 4 + quad) ^ lw3) << 3)];
                        s[n] = __builtin_amdgcn_mfma_f32_16x16x32_bf16(qf[kc], kf, s[n],
                                                                       0, 0, 0);
                    }
                if (kt == nkt - 1) {    // diagonal tile: causal mask
#pragma unroll
                    for (int n = 0; n < 4; n++)
#pragma unroll
                        for (int r = 0; r < 4; r++)
                            if (ks0 + n * 16 + lrow > q0 + quad * 4 + r)
                                s[n][r] = -1e30f;
                }
                float alpha[4];
#pragma unroll
                for (int r = 0; r < 4; r++) {
                    float mx = fmaxf(fmaxf(s[0][r], s[1][r]), fmaxf(s[2][r], s[3][r]));
                    mx = fmaxf(mx, __shfl_xor(mx, 1));
                    mx = fmaxf(mx, __shfl_xor(mx, 2));
                    mx = fmaxf(mx, __shfl_xor(mx, 4));
                    mx = fmaxf(mx, __shfl_xor(mx, 8));
                    float mn = fmaxf(m_i[r], mx);
                    alpha[r] = exp2f(m_i[r] - mn);
                    m_i[r] = mn;
                    float rs = 0.f;
#pragma unroll
                    for (int n = 0; n < 4; n++) {
                        s[n][r] = exp2f(s[n][r] - mn);
                        rs += s[n][r];
                    }
                    rs += __shfl_xor(rs, 1);
                    rs += __shfl_xor(rs, 2);
                    rs += __shfl_xor(rs, 4);
                    rs += __shfl_xor(rs, 8);
                    l_i[r] = l_i[r] * alpha[r] + rs;
                }
                // P -> LDS (C-layout -> A-layout round trip, swizzled)
#pragma unroll
                for (int n = 0; n < 4; n++)
#pragma unroll
                    for (int r = 0; r < 4; r++) {
                        int rw = quad * 4 + r, col = n * 16 + lrow;
                        Ps[wave][rw * 64 + (((col >> 3) ^ (rw & 7)) << 3) + (col & 7)] =
                            f2bf(s[n][r]);
                    }
#pragma unroll
                for (int t = 0; t < 8; t++)
#pragma unroll
                    for (int r = 0; r < 4; r++) oacc[t][r] *= alpha[r];
                bf16x8 pf0 = *(const bf16x8*)&Ps[wave][lrow * 64 + ((quad ^ lw3) << 3)];
                bf16x8 pf1 = *(const bf16x8*)&Ps[wave][lrow * 64 + (((4 + quad) ^ lw3) << 3)];
#pragma unroll
                for (int t = 0; t < 8; t++) {
                    int dim = t * 16 + lrow;
                    bf16x8 v0 = *(const bf16x8*)&Vt[dim * 64 + ((quad ^ lw3) << 3)];
                    bf16x8 v1 = *(const bf16x8*)&Vt[dim * 64 + (((4 + quad) ^ lw3) << 3)];
                    oacc[t] = __builtin_amdgcn_mfma_f32_16x16x32_bf16(pf0, v0, oacc[t], 0, 0, 0);
                    oacc[t] = __builtin_amdgcn_mfma_f32_16x16x32_bf16(pf1, v1, oacc[t], 0, 0, 0);
                }
            }
            __syncthreads();
        }
        // epilogue for this unit
        float inv[4];
#pragma unroll
        for (int r = 0; r < 4; r++) inv[r] = 1.f / l_i[r];
#pragma unroll
        for (int t = 0; t < 8; t++)
#pragma unroll
            for (int r = 0; r < 4; r++) {
                int q = q0 + quad * 4 + r;
                ctxb[(size_t)(b * S_ + q) * (NH_ * HD_) + h * HD_ + t * 16 + lrow] =
                    f2bf(oacc[t][r] * inv[r]);
            }
    }
}

// ---------------- launch ----------------
extern "C" void kernel_launch(void* const* d_in, const int* in_sizes, int n_in,
                              void* d_out, int out_size, void* d_ws, size_t ws_size,
                              hipStream_t stream) {
    const float* hidden = (const float*)d_in[0];
    const float* Wqkv = (const float*)d_in[2];
    const float* bqkv = (const float*)d_in[3];
    const float* Wo   = (const float*)d_in[4];
    float* out = (float*)d_out;

    char* ws = (char*)d_ws;
    unsigned short* Xb    = (unsigned short*)ws;                         // 32 MB
    unsigned short* WqkvT = (unsigned short*)(ws + 33554432);            // 36 MB
    unsigned short* Qb    = (unsigned short*)(ws + 71303168);            // 32 MB
    unsigned short* Kb    = (unsigned short*)(ws + 104857600);           //  2 MB
    unsigned short* Vb    = (unsigned short*)(ws + 106954752);           //  2 MB
    unsigned short* ctxb  = (unsigned short*)(ws + 109051904);           // 32 MB
    unsigned short* WoT   = Xb;          // Xb dead after gemm_qkv

    // 1. hidden -> bf16
    convert_bf16<<<16384, 256, 0, stream>>>(hidden, Xb, (MROWS * H_) / 4);
    // 2. Wqkv [4096][4608] -> WqkvT bf16 [4608][4096]
    transpose_bf16<<<dim3(QKVD / 32, H_ / 32), 256, 0, stream>>>(Wqkv, WqkvT, H_, QKVD);
    // 3. QKV projection + bias + RoPE + pack (fused epilogue)
    gemm_qkv<<<dim3(QKVD / 128, MROWS / 128), 256, 0, stream>>>(Xb, WqkvT, bqkv,
                                                                Qb, Kb, Vb);
    // 4. Wo -> WoT bf16 (into Xb region, dead after gemm_qkv)
    transpose_bf16<<<dim3(H_ / 32, H_ / 32), 256, 0, stream>>>(Wo, WoT, NH_ * HD_, H_);
    // 5. flash attention -> ctx bf16 (paired q-blocks, uniform block duration)
    flash4<<<dim3(S_ / 128, NH_, B_), 256, 0, stream>>>(Qb, Kb, Vb, ctxb);
    // 6. output projection -> d_out fp32
    gemm_bt<0><<<dim3(H_ / 128, MROWS / 128), 256, 0, stream>>>(ctxb, WoT, nullptr, out,
                                                                MROWS, H_, NH_ * HD_);
}